// Round 17
// baseline (1108.739 us; speedup 1.0000x reference)
//
#include <hip/hip_runtime.h>
#include <hip/hip_bf16.h>

// ---------------- problem constants ----------------
#define NB   16          // batch
#define XS   29          // input spatial
#define HS   27          // h spatial (29-3+1)
#define HSP  19683       // 27^3
#define PSP  1000        // 10^3
#define RR   16000       // R = 16*1000
#define KTAP 729         // 9^3
#define SPTOT 314928     // NB*HSP

// hT layout: [icg 32][b 16][z 27][y 27][x 28 (27+pad)][ic 4] ushort
#define HT_SLOT   81648UL          // 27*27*28*4 ushort per (icg,b)
#define HT_TOTAL  41803776UL       // 512 * HT_SLOT (ushort)
#define HT_PLANE  3024             // 27*28*4 ushort per z-plane (6048 B)
// w2c layout: [icg 32][chunk 183][ocg 4][lane 64] granules of 8 ushort
//   chunk<162: (dzdy = chunk>>1, d0 = (chunk&1)*4); k16 = (dx = d0+2h+(j>>2), ic = j&3)
//   chunk>=162: dzq = chunk-162; k16 = (dzy = dzq*4+2h+(j>>2), ic = j&3), dx=8 (dzy>80 -> 0)
#define W2C_CH    2048             // ushort per chunk (4 ocg * 64 lanes * 8)
#define W2C_ICG   374784UL         // 183 * 2048

// ---------------- workspace layout (float units) ----------------
#define OFF_WT   0UL                       // w2c: 11.99M ushort
#define OFF_H    11943936UL                // hT: 41.8M ushort + tail pad
#define OFF_SP   52254720UL                // spart
#define OFF_U    54302720UL                // u[b][r][8]
#define OFF_PRI  56350720UL                // priors[b][c][r][16]
#define OFF_LOG  64542720UL                // logits
#define OFF_V    65055232UL
#define OFF_D0   65055744UL
#define OFF_D1   65056256UL
#define OFF_D2   65064448UL
#define OFF_D3   65097216UL
#define OFF_PP   65693056UL                // pcaps partials: 8*16000*128
#define OFF_D3P  82077056UL                // dec3 partials: 32*16*10240
#define OFF_D4P  87319936UL                // dec4 partials: 32*16*27000
#define OFF_D2P  101143936UL               // dec2 partials: 8*16*2048

typedef __attribute__((ext_vector_type(8))) short bf16x8;
typedef __attribute__((ext_vector_type(4))) float f32x4;
typedef __attribute__((ext_vector_type(16))) float f32x16;

#define GL2LDS16(g, l) __builtin_amdgcn_global_load_lds( \
    (const __attribute__((address_space(1))) void*)(g), \
    (__attribute__((address_space(3))) void*)(l), 16, 0, 0)

// ============ prep: w2c 32x32-MFMA B-fragment pack from pcaps_w[oc][ic][tap] ============
__global__ void prep_w2c(const float* __restrict__ w, ushort* __restrict__ w2c) {
    int gid = blockIdx.x * 256 + threadIdx.x;     // 1,499,136 total, exact grid
    int icg = gid / 46848;                        // 46848 = 183*4*64
    int r   = gid % 46848;
    int chunk = r / 256;
    int r2  = r % 256;
    int ocg = r2 >> 6, lane = r2 & 63;
    int h = lane >> 5, col = lane & 31;
    int oc = ocg * 32 + col;
    const float* wb = w + (size_t)oc * 93312 + (size_t)icg * 4 * KTAP;
    ushort vals[8];
    #pragma unroll
    for (int j = 0; j < 8; j++) {
        int ic = j & 3;
        float v = 0.f;
        if (chunk < 162) {
            int dzdy = chunk >> 1, d0 = (chunk & 1) * 4;
            int dx = d0 + 2 * h + (j >> 2);
            v = wb[ic * KTAP + dzdy * 9 + dx];
        } else {
            int dzy = (chunk - 162) * 4 + 2 * h + (j >> 2);
            if (dzy <= 80) v = wb[ic * KTAP + dzy * 9 + 8];
        }
        __hip_bfloat16 hv = __float2bfloat16(v);
        vals[j] = *(ushort*)&hv;
    }
    ushort* dst = w2c + (size_t)icg * W2C_ICG + (size_t)chunk * W2C_CH
                      + (size_t)(ocg * 64 + lane) * 8;
    #pragma unroll
    for (int j = 0; j < 8; j++) dst[j] = vals[j];
}

// ============ conv1 3x3x3 + bias + relu -> hT[icg][b][z][y][x pad28][ic4] ============
__global__ __launch_bounds__(256) void conv1_relu_t(const float* __restrict__ x,
                                                    const float* __restrict__ w,
                                                    const float* __restrict__ bias,
                                                    ushort* __restrict__ hT) {
    __shared__ ushort lt[32][132];
    int t = threadIdx.x;
    int c = t & 127;
    float wr[27];
    #pragma unroll
    for (int k = 0; k < 27; k++) wr[k] = w[c * 27 + k];
    float bv = bias[c];
    int sp0 = blockIdx.x * 32;
    #pragma unroll 4
    for (int i = 0; i < 16; i++) {
        int spl = i * 2 + (t >> 7);
        int spg = sp0 + spl;
        if (spg < SPTOT) {
            int b = spg / HSP, sp = spg % HSP;
            int z = sp / 729, y = (sp / 27) % 27, xx = sp % 27;
            const float* xb = x + (size_t)b * (XS * XS * XS) + ((size_t)z * XS + y) * XS + xx;
            float xv[27];
            #pragma unroll
            for (int dz = 0; dz < 3; dz++)
                #pragma unroll
                for (int dy = 0; dy < 3; dy++)
                    #pragma unroll
                    for (int dx = 0; dx < 3; dx++)
                        xv[(dz * 3 + dy) * 3 + dx] = xb[((size_t)dz * XS + dy) * XS + dx];
            float acc = bv;
            #pragma unroll
            for (int k = 0; k < 27; k++) acc = fmaf(xv[k], wr[k], acc);
            __hip_bfloat16 hv = __float2bfloat16(fmaxf(acc, 0.f));
            lt[spl][c] = *(ushort*)&hv;
        }
    }
    __syncthreads();
    #pragma unroll
    for (int q = 0; q < 4; q++) {
        int gidx = q * 256 + t;
        int icg = gidx >> 5, spl = gidx & 31;
        int spg = sp0 + spl;
        if (spg < SPTOT) {
            int b = spg / HSP, sp = spg % HSP;
            int z = sp / 729, y = (sp / 27) % 27, xx = sp % 27;
            *(short4*)(hT + (size_t)(icg * 16 + b) * HT_SLOT
                          + ((size_t)(z * 27 + y) * 28 + xx) * 4) =
                *(const short4*)&lt[spl][icg * 4];
        }
    }
}

// ============ pcaps direct conv, 32x32x16 MFMA (halved LDS A-traffic vs r15's 431us) ====
// Waves: 4 oc-groups (32 oc) x 2 frag-sets (frags 0..3 / 4..6 of 32 rows). A-frag:
// row=lane&31, k=(lane>>5)*8+j; k16 = (4 dx, 4 ic) contiguous 16B in hT layout.
__global__ __launch_bounds__(512, 4) void pcaps_conv(const ushort* __restrict__ hT,
                                                     const ushort* __restrict__ w2c,
                                                     float* __restrict__ pp) {
    __shared__ __align__(16) ushort AT[36288];       // 72,576 B -> 2 blocks/CU
    int t = threadIdx.x;
    int bid = blockIdx.x;
    int g = bid & 7;                                 // XCD-pinned weight octet
    int rest = bid >> 3;                             // 0..79
    int b = rest / 5, ozt = rest % 5;
    int z0 = ozt * 4;

    int lane = t & 63, wave = t >> 6;
    int ocg = wave >> 1, fh = wave & 1;              // oc-group, frag-set
    int NF = 4 - fh;                                 // 4 or 3 fragments
    int col = lane & 31, h = lane >> 5;

    // fragment row bases: f = fh*4 + fi, row = f*32 + col (clamped; stores guarded)
    int vox[4];
    #pragma unroll
    for (int fi = 0; fi < 4; fi++) {
        int r = (fh * 4 + fi) * 32 + col; if (r > 199) r = 199;
        int ozl = r / 100; int rem = r % 100;
        int oy = rem / 10, ox = rem % 10;
        vox[fi] = (2 * ozl) * 6048 + (2 * oy) * 224 + (2 * ox) * 8;
    }

    f32x16 acc[4];
    #pragma unroll
    for (int fi = 0; fi < 4; fi++) acc[fi] = (f32x16)0.f;

    for (int ph = 0; ph < 4; ++ph) {
        int icg = g * 4 + ph;
        const ushort* src = hT + (size_t)(icg * 16 + b) * HT_SLOT + (size_t)z0 * HT_PLANE;
        if (ph) __syncthreads();
        #pragma unroll
        for (int q = 0; q < 9; q++) {
            int gi = q * 512 + t;
            if (gi < 4536)
                GL2LDS16(src + (size_t)gi * 8, AT + (size_t)gi * 8);
        }
        asm volatile("s_waitcnt vmcnt(0)" ::: "memory");
        __syncthreads();

        const ushort* wB = w2c + (size_t)icg * W2C_ICG + (size_t)(ocg * 64 + lane) * 8;
        bf16x8 bv = *(const bf16x8*)wB;
        // main chunks: (dzdy, d0) pairs, K=16 = 4 dx x 4 ic, one b128 A-read per frag
        for (int c = 0; c < 162; ++c) {
            bf16x8 bvn = *(const bf16x8*)(wB + (size_t)(c + 1) * W2C_CH);
            int dzdy = c >> 1, d0 = (c & 1) * 4;
            int coff = (dzdy / 9) * 6048 + (dzdy % 9) * 224 + (d0 + 2 * h) * 8;
            #pragma unroll
            for (int fi = 0; fi < 4; fi++) {
                if (fi < NF) {
                    bf16x8 av = *(const bf16x8*)((const char*)AT + vox[fi] + coff);
                    acc[fi] = __builtin_amdgcn_mfma_f32_32x32x16_bf16(av, bv, acc[fi], 0, 0, 0);
                }
            }
            bv = bvn;
        }
        // dx=8 chunks: K=16 = 4 dzy x 4 ic; two b64 A-reads per frag
        for (int cidx = 162; cidx < 183; ++cidx) {
            bf16x8 bvn = *(const bf16x8*)(wB + (size_t)((cidx + 1 < 183) ? cidx + 1 : cidx) * W2C_CH);
            int dzq = cidx - 162;
            int dzy0 = dzq * 4 + 2 * h;
            int dzy1 = dzy0 + 1;
            int o0 = (dzy0 / 9) * 6048 + (dzy0 % 9) * 224 + 64;
            int o1 = (dzy1 / 9) * 6048 + (dzy1 % 9) * 224 + 64;
            #pragma unroll
            for (int fi = 0; fi < 4; fi++) {
                if (fi < NF) {
                    union { bf16x8 v; short4 s4[2]; } a;
                    a.s4[0] = *(const short4*)((const char*)AT + vox[fi] + o0);
                    a.s4[1] = *(const short4*)((const char*)AT + vox[fi] + o1);
                    acc[fi] = __builtin_amdgcn_mfma_f32_32x32x16_bf16(a.v, bv, acc[fi], 0, 0, 0);
                }
            }
            bv = bvn;
        }
    }

    // epilogue: C/D (m74/m101): col = lane&31, row32 = (reg&3) + 8*(reg>>2) + 4*h
    float* pg = pp + (size_t)g * 2048000;
    int mbase = b * 1000 + ozt * 200;
    #pragma unroll
    for (int fi = 0; fi < 4; fi++) {
        if (fi < NF) {
            int f = fh * 4 + fi;
            #pragma unroll
            for (int reg = 0; reg < 16; reg++) {
                int row32 = (reg & 3) + 8 * (reg >> 2) + 4 * h;
                int lr = f * 32 + row32;
                if (lr < 200)
                    pg[(size_t)(mbase + lr) * 128 + ocg * 32 + col] = acc[fi][reg];
            }
        }
    }
}

// ============ fused: reduce 8 partials + bias + squash -> u[b][r][8] ============
__global__ void squash_red(const float* __restrict__ pp, const float* __restrict__ pb,
                           float* __restrict__ u) {
    __shared__ float rowv[2][128];
    int t = threadIdx.x;
    int m = blockIdx.x * 2 + (t >> 7);               // 8000 blocks, exact
    int ch = t & 127;
    float v = pb[ch];
    #pragma unroll
    for (int g = 0; g < 8; g++) v += pp[(size_t)g * 2048000 + (size_t)m * 128 + ch];
    rowv[t >> 7][ch] = v;
    __syncthreads();
    if (t < 32) {
        int row = t >> 4, rq = t & 15;
        int mm = blockIdx.x * 2 + row;
        int b = mm / PSP, s = mm % PSP;
        float vals[8], ss = 0.f;
        #pragma unroll
        for (int i = 0; i < 8; i++) { float x = rowv[row][i * 16 + rq]; vals[i] = x; ss += x * x; }
        float n = sqrtf(ss);
        float sc = ss / (1.f + ss) / (n + 1e-8f);
        float* dst = u + ((size_t)b * RR + rq * 1000 + s) * 8;
        #pragma unroll
        for (int i = 0; i < 8; i++) dst[i] = vals[i] * sc;
    }
}

// ============ priors[b][c][r][16] = sum_i u[b][r][i] * rw[c][r][i][16] ============
__global__ void priors_k(const float* __restrict__ u, const float* __restrict__ rw,
                         float* __restrict__ pri) {
    __shared__ float wl[16][132];
    int bx = blockIdx.x; int c = bx / 1000; int r0 = (bx % 1000) * 16;
    int t = threadIdx.x;
    const float4* src = (const float4*)(rw + ((size_t)c * RR + r0) * 128);
    #pragma unroll
    for (int q = 0; q < 8; q++) {
        int idx = q * 256 + t;
        int row = idx >> 5, c4 = idx & 31;
        *(float4*)&wl[row][c4 * 4] = src[idx];
    }
    __syncthreads();
    int bb = t >> 4, rl = t & 15;
    const float* up = u + ((size_t)bb * RR + r0 + rl) * 8;
    float4 u0 = *(const float4*)up, u1 = *(const float4*)(up + 4);
    float uu[8] = {u0.x, u0.y, u0.z, u0.w, u1.x, u1.y, u1.z, u1.w};
    float out[16];
    #pragma unroll
    for (int o = 0; o < 16; o++) out[o] = 0.f;
    #pragma unroll
    for (int i = 0; i < 8; i++)
        #pragma unroll
        for (int o = 0; o < 16; o++) out[o] += uu[i] * wl[rl][i * 16 + o];
    float* dst = pri + ((size_t)(bb * 2 + c) * RR + r0 + rl) * 16;
    #pragma unroll
    for (int q = 0; q < 4; q++)
        *(float4*)&dst[q * 4] = make_float4(out[q*4], out[q*4+1], out[q*4+2], out[q*4+3]);
}

// ============ routing iter0: logits==0 -> probs=0.5; partials, no atomics ============
__global__ void route_s0(const float* __restrict__ pri, float* __restrict__ spart) {
    int b = blockIdx.x, chunk = blockIdx.y;
    int t = threadIdx.x, o = t & 15, rl = t >> 4;
    float acc0 = 0.f, acc1 = 0.f;
    for (int j = 0; j < 40; j++) {
        int r = chunk * 640 + j * 16 + rl;
        acc0 += pri[((size_t)(b * 2 + 0) * RR + r) * 16 + o];
        acc1 += pri[((size_t)(b * 2 + 1) * RR + r) * 16 + o];
    }
    __shared__ float red[2][16][17];
    red[0][rl][o] = acc0; red[1][rl][o] = acc1;
    __syncthreads();
    for (int step = 8; step >= 1; step >>= 1) {
        if (rl < step) {
            red[0][rl][o] += red[0][rl + step][o];
            red[1][rl][o] += red[1][rl + step][o];
        }
        __syncthreads();
    }
    if (rl == 0) {
        spart[((b * 25 + chunk) * 2 + 0) * 16 + o] = 0.5f * red[0][0][o];
        spart[((b * 25 + chunk) * 2 + 1) * 16 + o] = 0.5f * red[1][0][o];
    }
}

// ============ fused logit-update + softmax + s-pass (iters 1,2) ============
template<int MODE>
__global__ void route_iter(const float* __restrict__ pri, const float* __restrict__ v,
                           float* __restrict__ lg, float* __restrict__ spart) {
    int b = blockIdx.x, chunk = blockIdx.y;
    int t = threadIdx.x, o = t & 15, rl = t >> 4;
    float v0 = v[(b * 2 + 0) * 16 + o], v1 = v[(b * 2 + 1) * 16 + o];
    float acc0 = 0.f, acc1 = 0.f;
    for (int j = 0; j < 40; j++) {
        int r = chunk * 640 + j * 16 + rl;
        float p0 = pri[((size_t)(b * 2 + 0) * RR + r) * 16 + o];
        float p1 = pri[((size_t)(b * 2 + 1) * RR + r) * 16 + o];
        float d0 = p0 * v0, d1 = p1 * v1;
        #pragma unroll
        for (int w = 1; w < 16; w <<= 1) { d0 += __shfl_xor(d0, w); d1 += __shfl_xor(d1, w); }
        float l0, l1;
        if (MODE == 1) {
            l0 = d0; l1 = d1;
            if (o == 0) lg[(size_t)(b * 2 + 0) * RR + r] = d0;
            if (o == 1) lg[(size_t)(b * 2 + 1) * RR + r] = d1;
        } else {
            l0 = lg[(size_t)(b * 2 + 0) * RR + r] + d0;
            l1 = lg[(size_t)(b * 2 + 1) * RR + r] + d1;
        }
        float mx = fmaxf(l0, l1);
        float e0 = __expf(l0 - mx), e1 = __expf(l1 - mx);
        float inv = 1.f / (e0 + e1);
        acc0 += (e0 * inv) * p0;
        acc1 += (e1 * inv) * p1;
    }
    __shared__ float red[2][16][17];
    red[0][rl][o] = acc0; red[1][rl][o] = acc1;
    __syncthreads();
    for (int step = 8; step >= 1; step >>= 1) {
        if (rl < step) {
            red[0][rl][o] += red[0][rl + step][o];
            red[1][rl][o] += red[1][rl + step][o];
        }
        __syncthreads();
    }
    if (rl == 0) {
        spart[((b * 25 + chunk) * 2 + 0) * 16 + o] = red[0][0][o];
        spart[((b * 25 + chunk) * 2 + 1) * 16 + o] = red[1][0][o];
    }
}

// ============ reduce spart + squash -> v ============
__global__ void squash_v_parts(const float* __restrict__ spart, float* __restrict__ v) {
    int t = threadIdx.x;
    int bc = t >> 4, o = t & 15;
    int b = bc >> 1, c = bc & 1;
    float x = 0.f;
    for (int ch = 0; ch < 25; ch++) x += spart[((b * 25 + ch) * 2 + c) * 16 + o];
    __shared__ float sv[32][17];
    sv[bc][o] = x;
    __syncthreads();
    float ss = 0.f;
    #pragma unroll
    for (int i = 0; i < 16; i++) { float y = sv[bc][i]; ss += y * y; }
    float n = sqrtf(ss);
    float sc = ss / (1.f + ss) / (n + 1e-8f);
    v[bc * 16 + o] = x * sc;
}

// ============ final: squash_v + classes + argmax mask ============
__global__ void squash_v_cls(const float* __restrict__ spart, float* __restrict__ out,
                             float* __restrict__ d0) {
    int t = threadIdx.x;
    int bc = t >> 4, o = t & 15;
    int b = bc >> 1, c = bc & 1;
    float x = 0.f;
    for (int ch = 0; ch < 25; ch++) x += spart[((b * 25 + ch) * 2 + c) * 16 + o];
    __shared__ float sv[32][17];
    __shared__ float vv[32][17];
    __shared__ float cls[32];
    sv[bc][o] = x;
    __syncthreads();
    float ss = 0.f;
    #pragma unroll
    for (int i = 0; i < 16; i++) { float y = sv[bc][i]; ss += y * y; }
    float n = sqrtf(ss);
    float sc = ss / (1.f + ss) / (n + 1e-8f);
    vv[bc][o] = x * sc;
    __syncthreads();
    if (t < 32) {
        float s2 = 0.f;
        #pragma unroll
        for (int i = 0; i < 16; i++) { float y = vv[t][i]; s2 += y * y; }
        float nn = sqrtf(s2);
        cls[t] = nn; out[t] = nn;
    }
    __syncthreads();
    int bb = t >> 5, k = t & 31, cc = k >> 4;
    int win = (cls[bb * 2 + 1] > cls[bb * 2 + 0]) ? 1 : 0;
    d0[t] = (cc == win) ? vv[bb * 2 + cc][k & 15] : 0.f;
}

// ============ decoder layer1 (K=32, tiny) ============
template<int K>
__global__ void dec_small(const float* __restrict__ din, const float* __restrict__ W,
                          const float* __restrict__ bias, float* __restrict__ dout, int N) {
    __shared__ float dl[16 * K];
    int t = threadIdx.x;
    for (int i = t; i < 16 * K; i += 256) dl[i] = din[i];
    __syncthreads();
    int n = blockIdx.x * 256 + t;
    if (n >= N) return;
    float acc[16];
    float bv = bias[n];
    #pragma unroll
    for (int b = 0; b < 16; b++) acc[b] = bv;
    for (int k = 0; k < K; k++) {
        float w = W[(size_t)k * N + n];
        #pragma unroll
        for (int b = 0; b < 16; b++) acc[b] += dl[b * K + k] * w;
    }
    #pragma unroll
    for (int b = 0; b < 16; b++) dout[(size_t)b * N + n] = fmaxf(acc[b], 0.f);
}

// ============ decoder layer2 K-split (8 ks x 64 k): 64 blocks, partials ============
__global__ void dec_small_split(const float* __restrict__ din, const float* __restrict__ W,
                                float* __restrict__ part) {
    __shared__ float dl[16 * 64];
    int t = threadIdx.x;
    int ks = blockIdx.y;
    for (int i = t; i < 16 * 64; i += 256) {
        int b = i >> 6, kk = i & 63;
        dl[i] = din[b * 512 + ks * 64 + kk];
    }
    __syncthreads();
    int n = blockIdx.x * 256 + t;       // 8 n-blocks x 256 = 2048 exact
    float acc[16];
    #pragma unroll
    for (int b = 0; b < 16; b++) acc[b] = 0.f;
    for (int kk = 0; kk < 64; kk++) {
        float w = W[(size_t)(ks * 64 + kk) * 2048 + n];
        #pragma unroll
        for (int b = 0; b < 16; b++) acc[b] += dl[b * 64 + kk] * w;
    }
    #pragma unroll
    for (int b = 0; b < 16; b++)
        part[((size_t)(ks * 16 + b)) * 2048 + n] = acc[b];
}

// ============ decoder big layers: K-split, no atomics, float4 W ============
__global__ void dec_split(const float* __restrict__ din, const float* __restrict__ W,
                          float* __restrict__ part, int N, int K, int KC) {
    extern __shared__ float dl[];
    int t = threadIdx.x;
    int ky = blockIdx.y;
    int k0 = ky * KC;
    for (int i = t; i < 16 * KC; i += 256) {
        int b = i / KC, kk = i % KC;
        dl[i] = din[(size_t)b * K + k0 + kk];
    }
    __syncthreads();
    int n = blockIdx.x * 1024 + t * 4;
    if (n >= N) return;
    float4 acc[16];
    #pragma unroll
    for (int b = 0; b < 16; b++) acc[b] = make_float4(0.f, 0.f, 0.f, 0.f);
    const float* Wp = W + (size_t)k0 * N + n;
    for (int kk = 0; kk < KC; kk++) {
        float4 w = *(const float4*)&Wp[(size_t)kk * N];
        #pragma unroll
        for (int b = 0; b < 16; b++) {
            float dv = dl[b * KC + kk];
            acc[b].x += dv * w.x; acc[b].y += dv * w.y;
            acc[b].z += dv * w.z; acc[b].w += dv * w.w;
        }
    }
    #pragma unroll
    for (int b = 0; b < 16; b++)
        *(float4*)&part[((size_t)(ky * 16 + b)) * N + n] = acc[b];
}

// ============ sum KY ky-partials + bias + activation ============
__global__ void bias_act_sum(const float* __restrict__ part, const float* __restrict__ bias,
                             float* __restrict__ out, int N, int total, int sigm, int KY) {
    int gid = blockIdx.x * 256 + threadIdx.x;
    if (gid >= total) return;
    int b = gid / N, n = gid % N;
    float x = bias[n];
    for (int ky = 0; ky < KY; ky++)
        x += part[((size_t)(ky * 16 + b)) * N + n];
    out[gid] = sigm ? (1.f / (1.f + __expf(-x))) : fmaxf(x, 0.f);
}

// ================================================================
extern "C" void kernel_launch(void* const* d_in, const int* in_sizes, int n_in,
                              void* d_out, int out_size, void* d_ws, size_t ws_size,
                              hipStream_t stream) {
    const float* x        = (const float*)d_in[0];
    const float* conv1_w  = (const float*)d_in[1];
    const float* conv1_b  = (const float*)d_in[2];
    const float* pcaps_w  = (const float*)d_in[3];
    const float* pcaps_b  = (const float*)d_in[4];
    const float* route_w  = (const float*)d_in[5];
    const float* dec_w1   = (const float*)d_in[6];
    const float* dec_b1   = (const float*)d_in[7];
    const float* dec_w2   = (const float*)d_in[8];
    const float* dec_b2   = (const float*)d_in[9];
    const float* dec_w3   = (const float*)d_in[10];
    const float* dec_b3   = (const float*)d_in[11];
    const float* dec_w4   = (const float*)d_in[12];
    const float* dec_b4   = (const float*)d_in[13];
    float* out = (float*)d_out;

    float* ws = (float*)d_ws;
    ushort* w2c = (ushort*)(ws + OFF_WT);
    ushort* hT  = (ushort*)(ws + OFF_H);
    float* spart = ws + OFF_SP;
    float* u    = ws + OFF_U;
    float* pri  = ws + OFF_PRI;
    float* lg   = ws + OFF_LOG;
    float* v    = ws + OFF_V;
    float* d0   = ws + OFF_D0;
    float* d1   = ws + OFF_D1;
    float* d2   = ws + OFF_D2;
    float* d3   = ws + OFF_D3;
    float* pp   = ws + OFF_PP;
    float* d3p  = ws + OFF_D3P;
    float* d4p  = ws + OFF_D4P;
    float* d2p  = ws + OFF_D2P;

    // weight pack (32x32 B-fragments) + conv1 (hT layout) + tail pad zero
    prep_w2c<<<5856, 256, 0, stream>>>(pcaps_w, w2c);
    conv1_relu_t<<<9842, 256, 0, stream>>>(x, conv1_w, conv1_b, hT);
    hipMemsetAsync(hT + HT_TOTAL, 0, 8192, stream);

    // pcaps: direct conv with 32x32x16 MFMA, 8 partial octets
    pcaps_conv<<<640, 512, 0, stream>>>(hT, w2c, pp);
    squash_red<<<8000, 256, 0, stream>>>(pp, pcaps_b, u);

    // priors einsum
    priors_k<<<2000, 256, 0, stream>>>(u, route_w, pri);

    // routing: 3 iterations, fused, no memsets/atomics
    route_s0<<<dim3(16, 25), 256, 0, stream>>>(pri, spart);
    squash_v_parts<<<1, 512, 0, stream>>>(spart, v);
    route_iter<1><<<dim3(16, 25), 256, 0, stream>>>(pri, v, lg, spart);
    squash_v_parts<<<1, 512, 0, stream>>>(spart, v);
    route_iter<2><<<dim3(16, 25), 256, 0, stream>>>(pri, v, lg, spart);
    squash_v_cls<<<1, 512, 0, stream>>>(spart, out, d0);

    // decoder: layer1 tiny; layer2 K-split x8; layers 3/4 KY=32
    dec_small<32><<<2, 256, 0, stream>>>(d0, dec_w1, dec_b1, d1, 512);
    dec_small_split<<<dim3(8, 8), 256, 0, stream>>>(d1, dec_w2, d2p);
    bias_act_sum<<<(16 * 2048 + 255) / 256, 256, 0, stream>>>(d2p, dec_b2, d2, 2048, 16 * 2048, 0, 8);

    dec_split<<<dim3(10, 32), 256, 16 * 64 * sizeof(float), stream>>>(d2, dec_w3, d3p, 10240, 2048, 64);
    bias_act_sum<<<(16 * 10240 + 255) / 256, 256, 0, stream>>>(d3p, dec_b3, d3, 10240, 16 * 10240, 0, 32);

    dec_split<<<dim3(27, 32), 256, 16 * 320 * sizeof(float), stream>>>(d3, dec_w4, d4p, 27000, 10240, 320);
    bias_act_sum<<<(16 * 27000 + 255) / 256, 256, 0, stream>>>(d4p, dec_b4, out + 32, 27000, 16 * 27000, 1, 32);
}

// Round 18
// 1037.391 us; speedup vs baseline: 1.0688x; 1.0688x over previous
//
#include <hip/hip_runtime.h>
#include <hip/hip_bf16.h>

// ---------------- problem constants ----------------
#define NB   16          // batch
#define XS   29          // input spatial
#define HS   27          // h spatial (29-3+1)
#define HSP  19683       // 27^3
#define PSP  1000        // 10^3
#define RR   16000       // R = 16*1000
#define KTAP 729         // 9^3
#define SPTOT 314928     // NB*HSP
#define RCH  100         // routing chunks (was 25): 1600 blocks -> 6.25 waves/SIMD

// hT layout: [icg 32][b 16][z 27][y 27][x 28 (27+pad)][ic 4] ushort
#define HT_SLOT   81648UL          // 27*27*28*4 ushort per (icg,b)
#define HT_TOTAL  41803776UL       // 512 * HT_SLOT (ushort)
#define HT_PLANE  3024             // 27*28*4 ushort per z-plane (6048 B)
// w2b layout: [icg 32][chunk 92][kq 4][oc 128] granules of 8 ushort
#define W2B_CH    4096             // ushort per chunk (512 granules * 8)
#define W2B_ICG   376832UL         // 92 * 4096

// ---------------- workspace layout (float units) ----------------
#define OFF_WT   0UL                       // w2b: 12.06M ushort
#define OFF_H    11943936UL                // hT: 41.8M ushort + tail pad
#define OFF_SP   52254720UL                // spart: 16*100*2*16 = 51,200
#define OFF_U    54302720UL                // u[b][r][8]
#define OFF_PRI  56350720UL                // priors[b][c][r][16]
#define OFF_LOG  64542720UL                // logits
#define OFF_V    65055232UL
#define OFF_D0   65055744UL
#define OFF_D1   65056256UL
#define OFF_D2   65064448UL
#define OFF_D3   65097216UL
#define OFF_PP   65693056UL                // pcaps partials: 8*16000*128
#define OFF_D3P  82077056UL                // dec3 partials: 32*16*10240
#define OFF_D4P  87319936UL                // dec4 partials: 32*16*27000
#define OFF_D2P  101143936UL               // dec2 partials: 8*16*2048

typedef __attribute__((ext_vector_type(8))) short bf16x8;
typedef __attribute__((ext_vector_type(4))) float f32x4;

#define GL2LDS16(g, l) __builtin_amdgcn_global_load_lds( \
    (const __attribute__((address_space(1))) void*)(g), \
    (__attribute__((address_space(3))) void*)(l), 16, 0, 0)

// ============ prep: w2b MFMA-fragment pack from pcaps_w[oc][ic][tap] ============
__global__ void prep_w2b(const float* __restrict__ w, ushort* __restrict__ w2b) {
    int gid = blockIdx.x * 256 + threadIdx.x;     // 1,507,328 total, exact grid
    int oc  = gid / 11776;                        // 11776 = 32*92*4
    int r   = gid % 11776;
    int icg = r / 368;
    int r2  = r % 368;
    int c = r2 >> 2, kq = r2 & 3;
    const float* wb = w + (size_t)oc * 93312 + (size_t)icg * 4 * KTAP;
    ushort vals[8];
    #pragma unroll
    for (int j = 0; j < 8; j++) {
        int ic = j & 3, half = j >> 2;
        float v = 0.f;
        if (c < 81) {
            int tap = c * 9 + 2 * kq + half;
            v = wb[ic * KTAP + tap];
        } else {
            int dzy = (c - 81) * 8 + 2 * kq + half;
            if (dzy <= 80) v = wb[ic * KTAP + dzy * 9 + 8];
        }
        __hip_bfloat16 hv = __float2bfloat16(v);
        vals[j] = *(ushort*)&hv;
    }
    ushort* dst = w2b + ((size_t)((icg * 92 + c) * 4 + kq) * 128 + oc) * 8;
    #pragma unroll
    for (int j = 0; j < 8; j++) dst[j] = vals[j];
}

// ============ conv1 3x3x3 + bias + relu -> hT[icg][b][z][y][x pad28][ic4] ============
__global__ __launch_bounds__(256) void conv1_relu_t(const float* __restrict__ x,
                                                    const float* __restrict__ w,
                                                    const float* __restrict__ bias,
                                                    ushort* __restrict__ hT) {
    __shared__ ushort lt[32][132];
    int t = threadIdx.x;
    int c = t & 127;
    float wr[27];
    #pragma unroll
    for (int k = 0; k < 27; k++) wr[k] = w[c * 27 + k];
    float bv = bias[c];
    int sp0 = blockIdx.x * 32;
    #pragma unroll 4
    for (int i = 0; i < 16; i++) {
        int spl = i * 2 + (t >> 7);
        int spg = sp0 + spl;
        if (spg < SPTOT) {
            int b = spg / HSP, sp = spg % HSP;
            int z = sp / 729, y = (sp / 27) % 27, xx = sp % 27;
            const float* xb = x + (size_t)b * (XS * XS * XS) + ((size_t)z * XS + y) * XS + xx;
            float xv[27];
            #pragma unroll
            for (int dz = 0; dz < 3; dz++)
                #pragma unroll
                for (int dy = 0; dy < 3; dy++)
                    #pragma unroll
                    for (int dx = 0; dx < 3; dx++)
                        xv[(dz * 3 + dy) * 3 + dx] = xb[((size_t)dz * XS + dy) * XS + dx];
            float acc = bv;
            #pragma unroll
            for (int k = 0; k < 27; k++) acc = fmaf(xv[k], wr[k], acc);
            __hip_bfloat16 hv = __float2bfloat16(fmaxf(acc, 0.f));
            lt[spl][c] = *(ushort*)&hv;
        }
    }
    __syncthreads();
    #pragma unroll
    for (int q = 0; q < 4; q++) {
        int gidx = q * 256 + t;
        int icg = gidx >> 5, spl = gidx & 31;
        int spg = sp0 + spl;
        if (spg < SPTOT) {
            int b = spg / HSP, sp = spg % HSP;
            int z = sp / 729, y = (sp / 27) % 27, xx = sp % 27;
            *(short4*)(hT + (size_t)(icg * 16 + b) * HT_SLOT
                          + ((size_t)(z * 27 + y) * 28 + xx) * 4) =
                *(const short4*)&lt[spl][icg * 4];
        }
    }
}

// ============ pcaps direct conv v1 (production, measured 431us; FROZEN) ============
__global__ __launch_bounds__(512, 4) void pcaps_conv(const ushort* __restrict__ hT,
                                                     const ushort* __restrict__ w2b,
                                                     float* __restrict__ pp) {
    __shared__ __align__(16) ushort AT[36288];       // 72,576 B
    int t = threadIdx.x;
    int bid = blockIdx.x;
    int g = bid & 7;                                 // XCD-pinned weight octet
    int rest = bid >> 3;                             // 0..79
    int b = rest / 5, ozt = rest % 5;
    int z0 = ozt * 4;

    int lane = t & 63, wave = t >> 6;
    int ocb = wave * 16;
    int l15 = lane & 15, kq = lane >> 4;

    int vox[13];
    #pragma unroll
    for (int f = 0; f < 13; f++) {
        int lr = f * 16 + l15; if (lr > 199) lr = 199;
        int ozl = lr / 100; int rem = lr % 100;
        int oy = rem / 10, ox = rem % 10;
        vox[f] = (2 * ozl) * 6048 + (2 * oy) * 224 + (2 * ox) * 8;
    }

    f32x4 acc[13];
    #pragma unroll
    for (int f = 0; f < 13; f++) acc[f] = (f32x4)0.f;

    int bvoff = (kq * 128 + ocb + l15) * 8;

    for (int ph = 0; ph < 4; ++ph) {
        int icg = g * 4 + ph;
        const ushort* src = hT + (size_t)(icg * 16 + b) * HT_SLOT + (size_t)z0 * HT_PLANE;
        if (ph) __syncthreads();
        #pragma unroll
        for (int q = 0; q < 9; q++) {
            int gi = q * 512 + t;
            if (gi < 4536)
                GL2LDS16(src + (size_t)gi * 8, AT + (size_t)gi * 8);
        }
        asm volatile("s_waitcnt vmcnt(0)" ::: "memory");
        __syncthreads();

        const ushort* wB = w2b + (size_t)icg * W2B_ICG;
        bf16x8 bv = *(const bf16x8*)(wB + bvoff);
        for (int c = 0; c < 81; ++c) {
            bf16x8 bvn = *(const bf16x8*)(wB + (size_t)(c + 1) * W2B_CH + bvoff);
            int coff = (c / 9) * 6048 + (c % 9) * 224 + kq * 16;
            #pragma unroll
            for (int f = 0; f < 13; f++) {
                bf16x8 av = *(const bf16x8*)((const char*)AT + vox[f] + coff);
                acc[f] = __builtin_amdgcn_mfma_f32_16x16x32_bf16(av, bv, acc[f], 0, 0, 0);
            }
            bv = bvn;
        }
        for (int cc = 0; cc < 11; ++cc) {
            int nxt = (cc == 10) ? 91 : 82 + cc;
            bf16x8 bvn = *(const bf16x8*)(wB + (size_t)nxt * W2B_CH + bvoff);
            int dzy0 = cc * 8 + 2 * kq;
            int dzy1 = dzy0 + 1;
            int o0 = (dzy0 / 9) * 6048 + (dzy0 % 9) * 224 + 64;
            int o1 = (dzy1 / 9) * 6048 + (dzy1 % 9) * 224 + 64;
            #pragma unroll
            for (int f = 0; f < 13; f++) {
                union { bf16x8 v; short4 h[2]; } a;
                a.h[0] = *(const short4*)((const char*)AT + vox[f] + o0);
                a.h[1] = *(const short4*)((const char*)AT + vox[f] + o1);
                acc[f] = __builtin_amdgcn_mfma_f32_16x16x32_bf16(a.v, bv, acc[f], 0, 0, 0);
            }
            bv = bvn;
        }
    }

    float* pg = pp + (size_t)g * 2048000;
    int mbase = b * 1000 + ozt * 200;
    #pragma unroll
    for (int f = 0; f < 13; f++) {
        #pragma unroll
        for (int r = 0; r < 4; r++) {
            int lr = f * 16 + kq * 4 + r;
            if (lr < 200)
                pg[(size_t)(mbase + lr) * 128 + ocb + l15] = acc[f][r];
        }
    }
}

// ============ fused: reduce 8 partials + bias + squash -> u[b][r][8] ============
__global__ void squash_red(const float* __restrict__ pp, const float* __restrict__ pb,
                           float* __restrict__ u) {
    __shared__ float rowv[2][128];
    int t = threadIdx.x;
    int m = blockIdx.x * 2 + (t >> 7);               // 8000 blocks, exact
    int ch = t & 127;
    float v = pb[ch];
    #pragma unroll
    for (int g = 0; g < 8; g++) v += pp[(size_t)g * 2048000 + (size_t)m * 128 + ch];
    rowv[t >> 7][ch] = v;
    __syncthreads();
    if (t < 32) {
        int row = t >> 4, rq = t & 15;
        int mm = blockIdx.x * 2 + row;
        int b = mm / PSP, s = mm % PSP;
        float vals[8], ss = 0.f;
        #pragma unroll
        for (int i = 0; i < 8; i++) { float x = rowv[row][i * 16 + rq]; vals[i] = x; ss += x * x; }
        float n = sqrtf(ss);
        float sc = ss / (1.f + ss) / (n + 1e-8f);
        float* dst = u + ((size_t)b * RR + rq * 1000 + s) * 8;
        #pragma unroll
        for (int i = 0; i < 8; i++) dst[i] = vals[i] * sc;
    }
}

// ============ priors[b][c][r][16] = sum_i u[b][r][i] * rw[c][r][i][16] ============
__global__ void priors_k(const float* __restrict__ u, const float* __restrict__ rw,
                         float* __restrict__ pri) {
    __shared__ float wl[16][132];
    int bx = blockIdx.x; int c = bx / 1000; int r0 = (bx % 1000) * 16;
    int t = threadIdx.x;
    const float4* src = (const float4*)(rw + ((size_t)c * RR + r0) * 128);
    #pragma unroll
    for (int q = 0; q < 8; q++) {
        int idx = q * 256 + t;
        int row = idx >> 5, c4 = idx & 31;
        *(float4*)&wl[row][c4 * 4] = src[idx];
    }
    __syncthreads();
    int bb = t >> 4, rl = t & 15;
    const float* up = u + ((size_t)bb * RR + r0 + rl) * 8;
    float4 u0 = *(const float4*)up, u1 = *(const float4*)(up + 4);
    float uu[8] = {u0.x, u0.y, u0.z, u0.w, u1.x, u1.y, u1.z, u1.w};
    float out[16];
    #pragma unroll
    for (int o = 0; o < 16; o++) out[o] = 0.f;
    #pragma unroll
    for (int i = 0; i < 8; i++)
        #pragma unroll
        for (int o = 0; o < 16; o++) out[o] += uu[i] * wl[rl][i * 16 + o];
    float* dst = pri + ((size_t)(bb * 2 + c) * RR + r0 + rl) * 16;
    #pragma unroll
    for (int q = 0; q < 4; q++)
        *(float4*)&dst[q * 4] = make_float4(out[q*4], out[q*4+1], out[q*4+2], out[q*4+3]);
}

// ============ routing iter0: logits==0 -> probs=0.5; RCH chunks, no atomics ============
__global__ void route_s0(const float* __restrict__ pri, float* __restrict__ spart) {
    int b = blockIdx.x, chunk = blockIdx.y;
    int t = threadIdx.x, o = t & 15, rl = t >> 4;
    float acc0 = 0.f, acc1 = 0.f;
    for (int j = 0; j < 10; j++) {
        int r = chunk * 160 + j * 16 + rl;
        acc0 += pri[((size_t)(b * 2 + 0) * RR + r) * 16 + o];
        acc1 += pri[((size_t)(b * 2 + 1) * RR + r) * 16 + o];
    }
    __shared__ float red[2][16][17];
    red[0][rl][o] = acc0; red[1][rl][o] = acc1;
    __syncthreads();
    for (int step = 8; step >= 1; step >>= 1) {
        if (rl < step) {
            red[0][rl][o] += red[0][rl + step][o];
            red[1][rl][o] += red[1][rl + step][o];
        }
        __syncthreads();
    }
    if (rl == 0) {
        spart[((b * RCH + chunk) * 2 + 0) * 16 + o] = 0.5f * red[0][0][o];
        spart[((b * RCH + chunk) * 2 + 1) * 16 + o] = 0.5f * red[1][0][o];
    }
}

// ============ fused logit-update + softmax + s-pass (iters 1,2) ============
template<int MODE>
__global__ void route_iter(const float* __restrict__ pri, const float* __restrict__ v,
                           float* __restrict__ lg, float* __restrict__ spart) {
    int b = blockIdx.x, chunk = blockIdx.y;
    int t = threadIdx.x, o = t & 15, rl = t >> 4;
    float v0 = v[(b * 2 + 0) * 16 + o], v1 = v[(b * 2 + 1) * 16 + o];
    float acc0 = 0.f, acc1 = 0.f;
    for (int j = 0; j < 10; j++) {
        int r = chunk * 160 + j * 16 + rl;
        float p0 = pri[((size_t)(b * 2 + 0) * RR + r) * 16 + o];
        float p1 = pri[((size_t)(b * 2 + 1) * RR + r) * 16 + o];
        float d0 = p0 * v0, d1 = p1 * v1;
        #pragma unroll
        for (int w = 1; w < 16; w <<= 1) { d0 += __shfl_xor(d0, w); d1 += __shfl_xor(d1, w); }
        float l0, l1;
        if (MODE == 1) {
            l0 = d0; l1 = d1;
            if (o == 0) lg[(size_t)(b * 2 + 0) * RR + r] = d0;
            if (o == 1) lg[(size_t)(b * 2 + 1) * RR + r] = d1;
        } else {
            l0 = lg[(size_t)(b * 2 + 0) * RR + r] + d0;
            l1 = lg[(size_t)(b * 2 + 1) * RR + r] + d1;
        }
        float mx = fmaxf(l0, l1);
        float e0 = __expf(l0 - mx), e1 = __expf(l1 - mx);
        float inv = 1.f / (e0 + e1);
        acc0 += (e0 * inv) * p0;
        acc1 += (e1 * inv) * p1;
    }
    __shared__ float red[2][16][17];
    red[0][rl][o] = acc0; red[1][rl][o] = acc1;
    __syncthreads();
    for (int step = 8; step >= 1; step >>= 1) {
        if (rl < step) {
            red[0][rl][o] += red[0][rl + step][o];
            red[1][rl][o] += red[1][rl + step][o];
        }
        __syncthreads();
    }
    if (rl == 0) {
        spart[((b * RCH + chunk) * 2 + 0) * 16 + o] = red[0][0][o];
        spart[((b * RCH + chunk) * 2 + 1) * 16 + o] = red[1][0][o];
    }
}

// ============ reduce spart + squash -> v ============
__global__ void squash_v_parts(const float* __restrict__ spart, float* __restrict__ v) {
    int t = threadIdx.x;
    int bc = t >> 4, o = t & 15;
    int b = bc >> 1, c = bc & 1;
    float x = 0.f;
    for (int ch = 0; ch < RCH; ch++) x += spart[((b * RCH + ch) * 2 + c) * 16 + o];
    __shared__ float sv[32][17];
    sv[bc][o] = x;
    __syncthreads();
    float ss = 0.f;
    #pragma unroll
    for (int i = 0; i < 16; i++) { float y = sv[bc][i]; ss += y * y; }
    float n = sqrtf(ss);
    float sc = ss / (1.f + ss) / (n + 1e-8f);
    v[bc * 16 + o] = x * sc;
}

// ============ final: squash_v + classes + argmax mask ============
__global__ void squash_v_cls(const float* __restrict__ spart, float* __restrict__ out,
                             float* __restrict__ d0) {
    int t = threadIdx.x;
    int bc = t >> 4, o = t & 15;
    int b = bc >> 1, c = bc & 1;
    float x = 0.f;
    for (int ch = 0; ch < RCH; ch++) x += spart[((b * RCH + ch) * 2 + c) * 16 + o];
    __shared__ float sv[32][17];
    __shared__ float vv[32][17];
    __shared__ float cls[32];
    sv[bc][o] = x;
    __syncthreads();
    float ss = 0.f;
    #pragma unroll
    for (int i = 0; i < 16; i++) { float y = sv[bc][i]; ss += y * y; }
    float n = sqrtf(ss);
    float sc = ss / (1.f + ss) / (n + 1e-8f);
    vv[bc][o] = x * sc;
    __syncthreads();
    if (t < 32) {
        float s2 = 0.f;
        #pragma unroll
        for (int i = 0; i < 16; i++) { float y = vv[t][i]; s2 += y * y; }
        float nn = sqrtf(s2);
        cls[t] = nn; out[t] = nn;
    }
    __syncthreads();
    int bb = t >> 5, k = t & 31, cc = k >> 4;
    int win = (cls[bb * 2 + 1] > cls[bb * 2 + 0]) ? 1 : 0;
    d0[t] = (cc == win) ? vv[bb * 2 + cc][k & 15] : 0.f;
}

// ============ decoder layer1 (K=32, tiny) ============
template<int K>
__global__ void dec_small(const float* __restrict__ din, const float* __restrict__ W,
                          const float* __restrict__ bias, float* __restrict__ dout, int N) {
    __shared__ float dl[16 * K];
    int t = threadIdx.x;
    for (int i = t; i < 16 * K; i += 256) dl[i] = din[i];
    __syncthreads();
    int n = blockIdx.x * 256 + t;
    if (n >= N) return;
    float acc[16];
    float bv = bias[n];
    #pragma unroll
    for (int b = 0; b < 16; b++) acc[b] = bv;
    for (int k = 0; k < K; k++) {
        float w = W[(size_t)k * N + n];
        #pragma unroll
        for (int b = 0; b < 16; b++) acc[b] += dl[b * K + k] * w;
    }
    #pragma unroll
    for (int b = 0; b < 16; b++) dout[(size_t)b * N + n] = fmaxf(acc[b], 0.f);
}

// ============ decoder layer2 K-split (8 ks x 64 k): 64 blocks, partials ============
__global__ void dec_small_split(const float* __restrict__ din, const float* __restrict__ W,
                                float* __restrict__ part) {
    __shared__ float dl[16 * 64];
    int t = threadIdx.x;
    int ks = blockIdx.y;
    for (int i = t; i < 16 * 64; i += 256) {
        int b = i >> 6, kk = i & 63;
        dl[i] = din[b * 512 + ks * 64 + kk];
    }
    __syncthreads();
    int n = blockIdx.x * 256 + t;       // 8 n-blocks x 256 = 2048 exact
    float acc[16];
    #pragma unroll
    for (int b = 0; b < 16; b++) acc[b] = 0.f;
    for (int kk = 0; kk < 64; kk++) {
        float w = W[(size_t)(ks * 64 + kk) * 2048 + n];
        #pragma unroll
        for (int b = 0; b < 16; b++) acc[b] += dl[b * 64 + kk] * w;
    }
    #pragma unroll
    for (int b = 0; b < 16; b++)
        part[((size_t)(ks * 16 + b)) * 2048 + n] = acc[b];
}

// ============ decoder big layers: K-split, no atomics, float4 W ============
__global__ void dec_split(const float* __restrict__ din, const float* __restrict__ W,
                          float* __restrict__ part, int N, int K, int KC) {
    extern __shared__ float dl[];
    int t = threadIdx.x;
    int ky = blockIdx.y;
    int k0 = ky * KC;
    for (int i = t; i < 16 * KC; i += 256) {
        int b = i / KC, kk = i % KC;
        dl[i] = din[(size_t)b * K + k0 + kk];
    }
    __syncthreads();
    int n = blockIdx.x * 1024 + t * 4;
    if (n >= N) return;
    float4 acc[16];
    #pragma unroll
    for (int b = 0; b < 16; b++) acc[b] = make_float4(0.f, 0.f, 0.f, 0.f);
    const float* Wp = W + (size_t)k0 * N + n;
    for (int kk = 0; kk < KC; kk++) {
        float4 w = *(const float4*)&Wp[(size_t)kk * N];
        #pragma unroll
        for (int b = 0; b < 16; b++) {
            float dv = dl[b * KC + kk];
            acc[b].x += dv * w.x; acc[b].y += dv * w.y;
            acc[b].z += dv * w.z; acc[b].w += dv * w.w;
        }
    }
    #pragma unroll
    for (int b = 0; b < 16; b++)
        *(float4*)&part[((size_t)(ky * 16 + b)) * N + n] = acc[b];
}

// ============ sum KY ky-partials + bias + activation ============
__global__ void bias_act_sum(const float* __restrict__ part, const float* __restrict__ bias,
                             float* __restrict__ out, int N, int total, int sigm, int KY) {
    int gid = blockIdx.x * 256 + threadIdx.x;
    if (gid >= total) return;
    int b = gid / N, n = gid % N;
    float x = bias[n];
    for (int ky = 0; ky < KY; ky++)
        x += part[((size_t)(ky * 16 + b)) * N + n];
    out[gid] = sigm ? (1.f / (1.f + __expf(-x))) : fmaxf(x, 0.f);
}

// ================================================================
extern "C" void kernel_launch(void* const* d_in, const int* in_sizes, int n_in,
                              void* d_out, int out_size, void* d_ws, size_t ws_size,
                              hipStream_t stream) {
    const float* x        = (const float*)d_in[0];
    const float* conv1_w  = (const float*)d_in[1];
    const float* conv1_b  = (const float*)d_in[2];
    const float* pcaps_w  = (const float*)d_in[3];
    const float* pcaps_b  = (const float*)d_in[4];
    const float* route_w  = (const float*)d_in[5];
    const float* dec_w1   = (const float*)d_in[6];
    const float* dec_b1   = (const float*)d_in[7];
    const float* dec_w2   = (const float*)d_in[8];
    const float* dec_b2   = (const float*)d_in[9];
    const float* dec_w3   = (const float*)d_in[10];
    const float* dec_b3   = (const float*)d_in[11];
    const float* dec_w4   = (const float*)d_in[12];
    const float* dec_b4   = (const float*)d_in[13];
    float* out = (float*)d_out;

    float* ws = (float*)d_ws;
    ushort* w2b = (ushort*)(ws + OFF_WT);
    ushort* hT  = (ushort*)(ws + OFF_H);
    float* spart = ws + OFF_SP;
    float* u    = ws + OFF_U;
    float* pri  = ws + OFF_PRI;
    float* lg   = ws + OFF_LOG;
    float* v    = ws + OFF_V;
    float* d0   = ws + OFF_D0;
    float* d1   = ws + OFF_D1;
    float* d2   = ws + OFF_D2;
    float* d3   = ws + OFF_D3;
    float* pp   = ws + OFF_PP;
    float* d3p  = ws + OFF_D3P;
    float* d4p  = ws + OFF_D4P;
    float* d2p  = ws + OFF_D2P;

    // weight pack + conv1 (hT layout) + tail pad zero (staging over-read safety)
    prep_w2b<<<5888, 256, 0, stream>>>(pcaps_w, w2b);
    conv1_relu_t<<<9842, 256, 0, stream>>>(x, conv1_w, conv1_b, hT);
    hipMemsetAsync(hT + HT_TOTAL, 0, 8192, stream);

    // pcaps: production direct conv (measured 431us; frozen), 8 partial octets
    pcaps_conv<<<640, 512, 0, stream>>>(hT, w2b, pp);
    squash_red<<<8000, 256, 0, stream>>>(pp, pcaps_b, u);

    // priors einsum
    priors_k<<<2000, 256, 0, stream>>>(u, route_w, pri);

    // routing: 3 iterations, RCH=100 chunks (6.25 waves/SIMD vs 1.56 at 25)
    route_s0<<<dim3(16, RCH), 256, 0, stream>>>(pri, spart);
    squash_v_parts<<<1, 512, 0, stream>>>(spart, v);
    route_iter<1><<<dim3(16, RCH), 256, 0, stream>>>(pri, v, lg, spart);
    squash_v_parts<<<1, 512, 0, stream>>>(spart, v);
    route_iter<2><<<dim3(16, RCH), 256, 0, stream>>>(pri, v, lg, spart);
    squash_v_cls<<<1, 512, 0, stream>>>(spart, out, d0);

    // decoder: layer1 tiny; layer2 K-split x8; layers 3/4 KY=32
    dec_small<32><<<2, 256, 0, stream>>>(d0, dec_w1, dec_b1, d1, 512);
    dec_small_split<<<dim3(8, 8), 256, 0, stream>>>(d1, dec_w2, d2p);
    bias_act_sum<<<(16 * 2048 + 255) / 256, 256, 0, stream>>>(d2p, dec_b2, d2, 2048, 16 * 2048, 0, 8);

    dec_split<<<dim3(10, 32), 256, 16 * 64 * sizeof(float), stream>>>(d2, dec_w3, d3p, 10240, 2048, 64);
    bias_act_sum<<<(16 * 10240 + 255) / 256, 256, 0, stream>>>(d3p, dec_b3, d3, 10240, 16 * 10240, 0, 32);

    dec_split<<<dim3(27, 32), 256, 16 * 320 * sizeof(float), stream>>>(d3, dec_w4, d4p, 27000, 10240, 320);
    bias_act_sum<<<(16 * 27000 + 255) / 256, 256, 0, stream>>>(d4p, dec_b4, out + 32, 27000, 16 * 27000, 1, 32);
}